// Round 1
// baseline (1885.962 us; speedup 1.0000x reference)
//
#include <hip/hip_runtime.h>
#include <cstdint>

// ---------------------------------------------------------------------------
// MultiModalClinicalGCN — fp32 baseline
//   m  = relu(mel @ W_mel + b_mel)                      [N,128]
//   x2 = relu([clinical|m] @ W_cat + b_cat)             [N,128]
//   h  = x2 @ W1                                        [N,128]
//   x3 = relu(scatter(norm*h) + dinv^2*h + b1)          [N,128]
//   y  = x3 @ W2                                        [N,4]
//   out= scatter(norm*y) + dinv^2*y + b2                [N,4]
// ---------------------------------------------------------------------------

// Detect int64-vs-int32 edge_index on device (int64 => odd 32-bit words are 0),
// convert to packed int32 [src(E) | dst(E)].
__global__ __launch_bounds__(256) void convert_edges_k(const int* __restrict__ ei,
                                                       int* __restrict__ sd, int twoE) {
  int nz = 0;
#pragma unroll
  for (int i = 1; i < 64; i += 2) nz |= ei[i];
  const bool is64 = (nz == 0);
  int e = blockIdx.x * 256 + threadIdx.x;
  if (e < twoE) sd[e] = is64 ? ei[2 * e] : ei[e];
}

__global__ __launch_bounds__(256) void fill_ones_k(float* __restrict__ p, int n) {
  int i = blockIdx.x * 256 + threadIdx.x;
  if (i < n) p[i] = 1.0f;
}

__global__ __launch_bounds__(256) void zero_k(float* __restrict__ p, int n) {
  int i = blockIdx.x * 256 + threadIdx.x;
  if (i < n) p[i] = 0.0f;
}

__global__ __launch_bounds__(256) void count_deg_k(const int* __restrict__ dst,
                                                   float* __restrict__ deg, int E) {
  int e = blockIdx.x * 256 + threadIdx.x;
  if (e < E) atomicAdd(&deg[dst[e]], 1.0f);
}

__global__ __launch_bounds__(256) void rsqrt_k(float* __restrict__ p, int n) {
  int i = blockIdx.x * 256 + threadIdx.x;
  if (i < n) p[i] = rsqrtf(p[i]);
}

// ---------------------------------------------------------------------------
// Tiled fp32 GEMM: C[n,128] = act(A[n,K] @ B[K,128] + bias)
// Block = 256 threads computes 64 rows x 128 cols. BK = 32.
// Thread (ty=tid>>5, tx=tid&31): 8 rows x 4 cols accumulators.
// ---------------------------------------------------------------------------
template <bool RELU, bool HASBIAS>
__global__ __launch_bounds__(256) void gemm128_k(const float* __restrict__ A, int K,
                                                 const float* __restrict__ B,
                                                 const float* __restrict__ bias,
                                                 float* __restrict__ C, int n) {
  __shared__ float As[64][33];
  __shared__ float4 Bs[32][32];
  const int tid = threadIdx.x;
  const int tx = tid & 31, ty = tid >> 5;
  const int row0 = blockIdx.x * 64;
  float acc[8][4];
#pragma unroll
  for (int i = 0; i < 8; ++i)
#pragma unroll
    for (int j = 0; j < 4; ++j) acc[i][j] = 0.f;

  const int nChunks = K >> 5;
  for (int kc = 0; kc < nChunks; ++kc) {
    __syncthreads();
#pragma unroll
    for (int j = 0; j < 2; ++j) {
      int idx = tid + j * 256;          // 0..511
      int ar = idx >> 3, ac4 = idx & 7; // 64 rows x 8 float4
      int grow = row0 + ar;
      float4 v = make_float4(0.f, 0.f, 0.f, 0.f);
      if (grow < n) v = *(const float4*)(A + (size_t)grow * K + kc * 32 + ac4 * 4);
      As[ar][ac4 * 4 + 0] = v.x;
      As[ar][ac4 * 4 + 1] = v.y;
      As[ar][ac4 * 4 + 2] = v.z;
      As[ar][ac4 * 4 + 3] = v.w;
    }
#pragma unroll
    for (int j = 0; j < 4; ++j) {
      int idx = tid + j * 256;            // 0..1023
      int br = idx >> 5, bc4 = idx & 31;  // 32 rows x 32 float4
      Bs[br][bc4] = *(const float4*)(B + (size_t)(kc * 32 + br) * 128 + bc4 * 4);
    }
    __syncthreads();
#pragma unroll
    for (int kk = 0; kk < 32; ++kk) {
      float4 b = Bs[kk][tx];
#pragma unroll
      for (int i = 0; i < 8; ++i) {
        float a = As[ty * 8 + i][kk];
        acc[i][0] += a * b.x;
        acc[i][1] += a * b.y;
        acc[i][2] += a * b.z;
        acc[i][3] += a * b.w;
      }
    }
  }
  float4 bb = make_float4(0.f, 0.f, 0.f, 0.f);
  if (HASBIAS) bb = *(const float4*)(bias + tx * 4);
#pragma unroll
  for (int i = 0; i < 8; ++i) {
    int grow = row0 + ty * 8 + i;
    if (grow < n) {
      float4 o;
      o.x = acc[i][0] + bb.x;
      o.y = acc[i][1] + bb.y;
      o.z = acc[i][2] + bb.z;
      o.w = acc[i][3] + bb.w;
      if (RELU) {
        o.x = fmaxf(o.x, 0.f);
        o.y = fmaxf(o.y, 0.f);
        o.z = fmaxf(o.z, 0.f);
        o.w = fmaxf(o.w, 0.f);
      }
      *(float4*)(C + (size_t)grow * 128 + tx * 4) = o;
    }
  }
}

// Same GEMM, but A = [clinical(64) | m(128)] fused (K = 192), relu + bias.
__global__ __launch_bounds__(256) void gemm_cat_k(const float* __restrict__ A1,
                                                  const float* __restrict__ A2,
                                                  const float* __restrict__ B,
                                                  const float* __restrict__ bias,
                                                  float* __restrict__ C, int n) {
  __shared__ float As[64][33];
  __shared__ float4 Bs[32][32];
  const int tid = threadIdx.x;
  const int tx = tid & 31, ty = tid >> 5;
  const int row0 = blockIdx.x * 64;
  float acc[8][4];
#pragma unroll
  for (int i = 0; i < 8; ++i)
#pragma unroll
    for (int j = 0; j < 4; ++j) acc[i][j] = 0.f;

  for (int kc = 0; kc < 6; ++kc) {  // K = 192
    __syncthreads();
#pragma unroll
    for (int j = 0; j < 2; ++j) {
      int idx = tid + j * 256;
      int ar = idx >> 3, ac4 = idx & 7;
      int grow = row0 + ar;
      int kcol = kc * 32 + ac4 * 4;
      float4 v = make_float4(0.f, 0.f, 0.f, 0.f);
      if (grow < n) {
        v = (kcol < 64) ? *(const float4*)(A1 + (size_t)grow * 64 + kcol)
                        : *(const float4*)(A2 + (size_t)grow * 128 + (kcol - 64));
      }
      As[ar][ac4 * 4 + 0] = v.x;
      As[ar][ac4 * 4 + 1] = v.y;
      As[ar][ac4 * 4 + 2] = v.z;
      As[ar][ac4 * 4 + 3] = v.w;
    }
#pragma unroll
    for (int j = 0; j < 4; ++j) {
      int idx = tid + j * 256;
      int br = idx >> 5, bc4 = idx & 31;
      Bs[br][bc4] = *(const float4*)(B + (size_t)(kc * 32 + br) * 128 + bc4 * 4);
    }
    __syncthreads();
#pragma unroll
    for (int kk = 0; kk < 32; ++kk) {
      float4 b = Bs[kk][tx];
#pragma unroll
      for (int i = 0; i < 8; ++i) {
        float a = As[ty * 8 + i][kk];
        acc[i][0] += a * b.x;
        acc[i][1] += a * b.y;
        acc[i][2] += a * b.z;
        acc[i][3] += a * b.w;
      }
    }
  }
  float4 bb = *(const float4*)(bias + tx * 4);
#pragma unroll
  for (int i = 0; i < 8; ++i) {
    int grow = row0 + ty * 8 + i;
    if (grow < n) {
      float4 o;
      o.x = fmaxf(acc[i][0] + bb.x, 0.f);
      o.y = fmaxf(acc[i][1] + bb.y, 0.f);
      o.z = fmaxf(acc[i][2] + bb.z, 0.f);
      o.w = fmaxf(acc[i][3] + bb.w, 0.f);
      *(float4*)(C + (size_t)grow * 128 + tx * 4) = o;
    }
  }
}

// Edge scatter for 128-wide features: 128 threads per edge (2 waves).
__global__ __launch_bounds__(256) void scatter128_k(const int* __restrict__ sd,
                                                    const float* __restrict__ dinv,
                                                    const float* __restrict__ h,
                                                    float* __restrict__ acc, int E) {
  unsigned gid = blockIdx.x * 256u + threadIdx.x;
  unsigned e = gid >> 7;
  int f = gid & 127;
  if (e < (unsigned)E) {
    int s = sd[e];
    int d = sd[E + e];
    float nrm = dinv[s] * dinv[d];
    atomicAdd(&acc[(size_t)d * 128 + f], nrm * h[(size_t)s * 128 + f]);
  }
}

// x3 = relu(acc + dinv^2 * h + b1), in place on acc.
__global__ __launch_bounds__(256) void finish1_k(float* __restrict__ acc,
                                                 const float* __restrict__ h,
                                                 const float* __restrict__ dinv,
                                                 const float* __restrict__ b1, int n) {
  int idx = blockIdx.x * 256 + threadIdx.x;
  if (idx < n * 128) {
    int row = idx >> 7;
    int f = idx & 127;
    float di = dinv[row];
    float v = acc[idx] + di * di * h[idx] + b1[f];
    acc[idx] = fmaxf(v, 0.f);
  }
}

// y[n,4] = A[n,128] @ W[128,4] ; thread per row, W staged in LDS.
__global__ __launch_bounds__(256) void gemm_small4_k(const float* __restrict__ A,
                                                     const float* __restrict__ W,
                                                     float* __restrict__ Y, int n) {
  __shared__ float Ws[512];
  int tid = threadIdx.x;
  Ws[tid] = W[tid];
  Ws[tid + 256] = W[tid + 256];
  __syncthreads();
  int row = blockIdx.x * 256 + tid;
  if (row >= n) return;
  const float4* A4 = (const float4*)(A + (size_t)row * 128);
  float a0 = 0.f, a1 = 0.f, a2 = 0.f, a3 = 0.f;
#pragma unroll
  for (int k4 = 0; k4 < 32; ++k4) {
    float4 a = A4[k4];
    const float* w = &Ws[k4 * 16];
    a0 += a.x * w[0] + a.y * w[4] + a.z * w[8] + a.w * w[12];
    a1 += a.x * w[1] + a.y * w[5] + a.z * w[9] + a.w * w[13];
    a2 += a.x * w[2] + a.y * w[6] + a.z * w[10] + a.w * w[14];
    a3 += a.x * w[3] + a.y * w[7] + a.z * w[11] + a.w * w[15];
  }
  *(float4*)(Y + (size_t)row * 4) = make_float4(a0, a1, a2, a3);
}

// Edge scatter for 4-wide features: 4 threads per edge.
__global__ __launch_bounds__(256) void scatter4_k(const int* __restrict__ sd,
                                                  const float* __restrict__ dinv,
                                                  const float* __restrict__ y,
                                                  float* __restrict__ out, int E) {
  unsigned gid = blockIdx.x * 256u + threadIdx.x;
  unsigned e = gid >> 2;
  int f = gid & 3;
  if (e < (unsigned)E) {
    int s = sd[e];
    int d = sd[E + e];
    float nrm = dinv[s] * dinv[d];
    atomicAdd(&out[(size_t)d * 4 + f], nrm * y[(size_t)s * 4 + f]);
  }
}

// out += dinv^2 * y + b2
__global__ __launch_bounds__(256) void finish2_k(float* __restrict__ out,
                                                 const float* __restrict__ y,
                                                 const float* __restrict__ dinv,
                                                 const float* __restrict__ b2, int n) {
  int idx = blockIdx.x * 256 + threadIdx.x;
  if (idx < n * 4) {
    int row = idx >> 2;
    int f = idx & 3;
    float di = dinv[row];
    out[idx] += di * di * y[idx] + b2[f];
  }
}

extern "C" void kernel_launch(void* const* d_in, const int* in_sizes, int n_in,
                              void* d_out, int out_size, void* d_ws, size_t ws_size,
                              hipStream_t stream) {
  const float* clinical = (const float*)d_in[0];
  const float* mel = (const float*)d_in[1];
  const int* ei = (const int*)d_in[2];
  const float* W_mel = (const float*)d_in[3];
  const float* b_mel = (const float*)d_in[4];
  const float* W_cat = (const float*)d_in[5];
  const float* b_cat = (const float*)d_in[6];
  const float* W1 = (const float*)d_in[7];
  const float* b1 = (const float*)d_in[8];
  const float* W2 = (const float*)d_in[9];
  const float* b2 = (const float*)d_in[10];
  float* out = (float*)d_out;

  const int N = in_sizes[0] / 64;   // 100000
  const int E = in_sizes[2] / 2;    // 1600000

  // Workspace layout (floats):
  //   bufA [N*128] | bufB [N*128] | dinv [N] | ybuf [N*4] | sd (int) [2E]
  float* bufA = (float*)d_ws;
  float* bufB = bufA + (size_t)N * 128;
  float* dinv = bufB + (size_t)N * 128;
  float* ybuf = dinv + N;
  int* sd = (int*)(ybuf + (size_t)N * 4);

  const dim3 blk(256);

  // Edge conversion + degree/dinv
  convert_edges_k<<<(2 * E + 255) / 256, blk, 0, stream>>>(ei, sd, 2 * E);
  fill_ones_k<<<(N + 255) / 256, blk, 0, stream>>>(dinv, N);
  count_deg_k<<<(E + 255) / 256, blk, 0, stream>>>(sd + E, dinv, E);
  rsqrt_k<<<(N + 255) / 256, blk, 0, stream>>>(dinv, N);

  // m = relu(mel @ W_mel + b_mel)        -> bufA
  gemm128_k<true, true><<<(N + 63) / 64, blk, 0, stream>>>(mel, 1024, W_mel, b_mel, bufA, N);
  // x2 = relu([clinical|m] @ W_cat + b)  -> bufB
  gemm_cat_k<<<(N + 63) / 64, blk, 0, stream>>>(clinical, bufA, W_cat, b_cat, bufB, N);
  // h = x2 @ W1                          -> bufA
  gemm128_k<false, false><<<(N + 63) / 64, blk, 0, stream>>>(bufB, 128, W1, nullptr, bufA, N);

  // propagate 1: acc(bufB) = sum norm*h[src]; then x3 = relu(acc + dinv^2*h + b1)
  zero_k<<<(N * 128 + 255) / 256, blk, 0, stream>>>(bufB, N * 128);
  {
    long long total = (long long)E * 128;
    scatter128_k<<<(unsigned)((total + 255) / 256), blk, 0, stream>>>(sd, dinv, bufA, bufB, E);
  }
  finish1_k<<<(N * 128 + 255) / 256, blk, 0, stream>>>(bufB, bufA, dinv, b1, N);

  // y = x3 @ W2                          -> ybuf
  gemm_small4_k<<<(N + 255) / 256, blk, 0, stream>>>(bufB, W2, ybuf, N);

  // propagate 2 into d_out
  zero_k<<<(N * 4 + 255) / 256, blk, 0, stream>>>(out, N * 4);
  {
    long long total = (long long)E * 4;
    scatter4_k<<<(unsigned)((total + 255) / 256), blk, 0, stream>>>(sd, dinv, ybuf, out, E);
  }
  finish2_k<<<(N * 4 + 255) / 256, blk, 0, stream>>>(out, ybuf, dinv, b2, N);
}

// Round 2
// 1311.288 us; speedup vs baseline: 1.4383x; 1.4383x over previous
//
#include <hip/hip_runtime.h>
#include <cstdint>

// ---------------------------------------------------------------------------
// MultiModalClinicalGCN — round 2: scatter->gather via per-call CSR(dst)
//   m  = relu(mel @ W_mel + b_mel)                      [N,128]
//   x2 = relu([clinical|m] @ W_cat + b_cat)             [N,128]
//   h  = x2 @ W1                                        [N,128]
//   x3 = relu(gather) : dinv[d]*(sum dinv[s]h[s]) + dinv[d]^2 h[d] + b1
//   y  = x3 @ W2                                        [N,4]
//   out= gather(no relu) on y + b2                      [N,4]
// ---------------------------------------------------------------------------

// edge_index may be int64 (viewed as int32 pairs, odd words all 0 since
// values < 100000) or int32. Detect per-kernel from the first 64 words.
__device__ __forceinline__ bool detect_i64(const int* __restrict__ ei) {
  int nz = 0;
#pragma unroll
  for (int i = 1; i < 64; i += 2) nz |= ei[i];
  return nz == 0;
}
__device__ __forceinline__ int load_src(const int* __restrict__ ei, int e, bool is64) {
  return is64 ? ei[2 * e] : ei[e];
}
__device__ __forceinline__ int load_dst(const int* __restrict__ ei, int e, int E, bool is64) {
  return is64 ? ei[2 * (E + e)] : ei[E + e];
}

__global__ __launch_bounds__(256) void zero_int_k(int* __restrict__ p, int n) {
  int i = blockIdx.x * 256 + threadIdx.x;
  if (i < n) p[i] = 0;
}

__global__ __launch_bounds__(256) void count_deg_k(const int* __restrict__ ei,
                                                   int* __restrict__ degi, int E) {
  const bool is64 = detect_i64(ei);
  int e = blockIdx.x * 256 + threadIdx.x;
  if (e < E) atomicAdd(&degi[load_dst(ei, e, E, is64)], 1);
}

__global__ __launch_bounds__(256) void dinv_k(const int* __restrict__ degi,
                                              float* __restrict__ dinv, int n) {
  int i = blockIdx.x * 256 + threadIdx.x;
  if (i < n) dinv[i] = rsqrtf((float)degi[i] + 1.0f);  // +1 self-loop
}

// ---- 3-kernel exclusive scan of degi[n] -> rowptr[n] (rowptr[n]=E set later)
__global__ __launch_bounds__(256) void scan_reduce_k(const int* __restrict__ degi,
                                                     int* __restrict__ partial, int n) {
  __shared__ int s[256];
  int t = threadIdx.x;
  int i = blockIdx.x * 256 + t;
  s[t] = (i < n) ? degi[i] : 0;
  __syncthreads();
#pragma unroll
  for (int off = 128; off > 0; off >>= 1) {
    if (t < off) s[t] += s[t + off];
    __syncthreads();
  }
  if (t == 0) partial[blockIdx.x] = s[0];
}

// one block, 512 threads: exclusive scan of partial[B] -> excl[B]; rowptr[n]=E
__global__ __launch_bounds__(512) void scan_partials_k(const int* __restrict__ partial,
                                                       int* __restrict__ excl, int B,
                                                       int* __restrict__ rowptr, int n, int E) {
  __shared__ int s[512];
  int t = threadIdx.x;
  int v = (t < B) ? partial[t] : 0;
  s[t] = v;
  __syncthreads();
  for (int off = 1; off < 512; off <<= 1) {
    int x = (t >= off) ? s[t - off] : 0;
    __syncthreads();
    s[t] += x;
    __syncthreads();
  }
  if (t < B) excl[t] = s[t] - v;
  if (t == 0) rowptr[n] = E;
}

__global__ __launch_bounds__(256) void scan_final_k(const int* __restrict__ degi,
                                                    const int* __restrict__ excl,
                                                    int* __restrict__ rowptr, int n) {
  __shared__ int s[256];
  int t = threadIdx.x;
  int i = blockIdx.x * 256 + t;
  int v = (i < n) ? degi[i] : 0;
  s[t] = v;
  __syncthreads();
  for (int off = 1; off < 256; off <<= 1) {
    int x = (t >= off) ? s[t - off] : 0;
    __syncthreads();
    s[t] += x;
    __syncthreads();
  }
  if (i < n) rowptr[i] = excl[blockIdx.x] + s[t] - v;
}

// col[rowptr[d] + k] = src for each in-edge of d
__global__ __launch_bounds__(256) void fill_col_k(const int* __restrict__ ei,
                                                  const int* __restrict__ rowptr,
                                                  int* __restrict__ fill,
                                                  int* __restrict__ col, int E) {
  const bool is64 = detect_i64(ei);
  int e = blockIdx.x * 256 + threadIdx.x;
  if (e < E) {
    int s = load_src(ei, e, is64);
    int d = load_dst(ei, e, E, is64);
    int pos = rowptr[d] + atomicAdd(&fill[d], 1);
    col[pos] = s;
  }
}

// ---------------------------------------------------------------------------
// Tiled fp32 GEMM: C[n,128] = act(A[n,K] @ B[K,128] + bias)  (unchanged)
// ---------------------------------------------------------------------------
template <bool RELU, bool HASBIAS>
__global__ __launch_bounds__(256) void gemm128_k(const float* __restrict__ A, int K,
                                                 const float* __restrict__ B,
                                                 const float* __restrict__ bias,
                                                 float* __restrict__ C, int n) {
  __shared__ float As[64][33];
  __shared__ float4 Bs[32][32];
  const int tid = threadIdx.x;
  const int tx = tid & 31, ty = tid >> 5;
  const int row0 = blockIdx.x * 64;
  float acc[8][4];
#pragma unroll
  for (int i = 0; i < 8; ++i)
#pragma unroll
    for (int j = 0; j < 4; ++j) acc[i][j] = 0.f;

  const int nChunks = K >> 5;
  for (int kc = 0; kc < nChunks; ++kc) {
    __syncthreads();
#pragma unroll
    for (int j = 0; j < 2; ++j) {
      int idx = tid + j * 256;
      int ar = idx >> 3, ac4 = idx & 7;
      int grow = row0 + ar;
      float4 v = make_float4(0.f, 0.f, 0.f, 0.f);
      if (grow < n) v = *(const float4*)(A + (size_t)grow * K + kc * 32 + ac4 * 4);
      As[ar][ac4 * 4 + 0] = v.x;
      As[ar][ac4 * 4 + 1] = v.y;
      As[ar][ac4 * 4 + 2] = v.z;
      As[ar][ac4 * 4 + 3] = v.w;
    }
#pragma unroll
    for (int j = 0; j < 4; ++j) {
      int idx = tid + j * 256;
      int br = idx >> 5, bc4 = idx & 31;
      Bs[br][bc4] = *(const float4*)(B + (size_t)(kc * 32 + br) * 128 + bc4 * 4);
    }
    __syncthreads();
#pragma unroll
    for (int kk = 0; kk < 32; ++kk) {
      float4 b = Bs[kk][tx];
#pragma unroll
      for (int i = 0; i < 8; ++i) {
        float a = As[ty * 8 + i][kk];
        acc[i][0] += a * b.x;
        acc[i][1] += a * b.y;
        acc[i][2] += a * b.z;
        acc[i][3] += a * b.w;
      }
    }
  }
  float4 bb = make_float4(0.f, 0.f, 0.f, 0.f);
  if (HASBIAS) bb = *(const float4*)(bias + tx * 4);
#pragma unroll
  for (int i = 0; i < 8; ++i) {
    int grow = row0 + ty * 8 + i;
    if (grow < n) {
      float4 o;
      o.x = acc[i][0] + bb.x;
      o.y = acc[i][1] + bb.y;
      o.z = acc[i][2] + bb.z;
      o.w = acc[i][3] + bb.w;
      if (RELU) {
        o.x = fmaxf(o.x, 0.f);
        o.y = fmaxf(o.y, 0.f);
        o.z = fmaxf(o.z, 0.f);
        o.w = fmaxf(o.w, 0.f);
      }
      *(float4*)(C + (size_t)grow * 128 + tx * 4) = o;
    }
  }
}

// A = [clinical(64) | m(128)] fused (K = 192), relu + bias.
__global__ __launch_bounds__(256) void gemm_cat_k(const float* __restrict__ A1,
                                                  const float* __restrict__ A2,
                                                  const float* __restrict__ B,
                                                  const float* __restrict__ bias,
                                                  float* __restrict__ C, int n) {
  __shared__ float As[64][33];
  __shared__ float4 Bs[32][32];
  const int tid = threadIdx.x;
  const int tx = tid & 31, ty = tid >> 5;
  const int row0 = blockIdx.x * 64;
  float acc[8][4];
#pragma unroll
  for (int i = 0; i < 8; ++i)
#pragma unroll
    for (int j = 0; j < 4; ++j) acc[i][j] = 0.f;

  for (int kc = 0; kc < 6; ++kc) {
    __syncthreads();
#pragma unroll
    for (int j = 0; j < 2; ++j) {
      int idx = tid + j * 256;
      int ar = idx >> 3, ac4 = idx & 7;
      int grow = row0 + ar;
      int kcol = kc * 32 + ac4 * 4;
      float4 v = make_float4(0.f, 0.f, 0.f, 0.f);
      if (grow < n) {
        v = (kcol < 64) ? *(const float4*)(A1 + (size_t)grow * 64 + kcol)
                        : *(const float4*)(A2 + (size_t)grow * 128 + (kcol - 64));
      }
      As[ar][ac4 * 4 + 0] = v.x;
      As[ar][ac4 * 4 + 1] = v.y;
      As[ar][ac4 * 4 + 2] = v.z;
      As[ar][ac4 * 4 + 3] = v.w;
    }
#pragma unroll
    for (int j = 0; j < 4; ++j) {
      int idx = tid + j * 256;
      int br = idx >> 5, bc4 = idx & 31;
      Bs[br][bc4] = *(const float4*)(B + (size_t)(kc * 32 + br) * 128 + bc4 * 4);
    }
    __syncthreads();
#pragma unroll
    for (int kk = 0; kk < 32; ++kk) {
      float4 b = Bs[kk][tx];
#pragma unroll
      for (int i = 0; i < 8; ++i) {
        float a = As[ty * 8 + i][kk];
        acc[i][0] += a * b.x;
        acc[i][1] += a * b.y;
        acc[i][2] += a * b.z;
        acc[i][3] += a * b.w;
      }
    }
  }
  float4 bb = *(const float4*)(bias + tx * 4);
#pragma unroll
  for (int i = 0; i < 8; ++i) {
    int grow = row0 + ty * 8 + i;
    if (grow < n) {
      float4 o;
      o.x = fmaxf(acc[i][0] + bb.x, 0.f);
      o.y = fmaxf(acc[i][1] + bb.y, 0.f);
      o.z = fmaxf(acc[i][2] + bb.z, 0.f);
      o.w = fmaxf(acc[i][3] + bb.w, 0.f);
      *(float4*)(C + (size_t)grow * 128 + tx * 4) = o;
    }
  }
}

// ---------------------------------------------------------------------------
// Gather-form propagate, 128 feats: 128 threads per node (block = 2 nodes).
// out[d,f] = relu( dinv[d]*(sum_s dinv[s]*h[s,f]) + dinv[d]^2*h[d,f] + b[f] )
// ---------------------------------------------------------------------------
template <bool RELU>
__global__ __launch_bounds__(256) void gather128_k(const int* __restrict__ col,
                                                   const int* __restrict__ rowptr,
                                                   const float* __restrict__ dinv,
                                                   const float* __restrict__ h,
                                                   const float* __restrict__ bias,
                                                   float* __restrict__ out, int n) {
  const int node = blockIdx.x * 2 + (threadIdx.x >> 7);
  const int f = threadIdx.x & 127;
  if (node >= n) return;
  const int beg = rowptr[node], end = rowptr[node + 1];
  float acc = 0.f;
  int p = beg;
  // unroll-4: 4 independent LLC row-gathers in flight
  for (; p + 4 <= end; p += 4) {
    int s0 = col[p], s1 = col[p + 1], s2 = col[p + 2], s3 = col[p + 3];
    float d0 = dinv[s0], d1 = dinv[s1], d2 = dinv[s2], d3 = dinv[s3];
    float h0 = h[(size_t)s0 * 128 + f];
    float h1 = h[(size_t)s1 * 128 + f];
    float h2 = h[(size_t)s2 * 128 + f];
    float h3 = h[(size_t)s3 * 128 + f];
    acc += d0 * h0 + d1 * h1 + d2 * h2 + d3 * h3;
  }
  for (; p < end; ++p) {
    int s = col[p];
    acc += dinv[s] * h[(size_t)s * 128 + f];
  }
  const float di = dinv[node];
  float v = di * (acc + di * h[(size_t)node * 128 + f]) + bias[f];
  if (RELU) v = fmaxf(v, 0.f);
  out[(size_t)node * 128 + f] = v;
}

// y[n,4] = A[n,128] @ W[128,4] ; thread per row, W staged in LDS.
__global__ __launch_bounds__(256) void gemm_small4_k(const float* __restrict__ A,
                                                     const float* __restrict__ W,
                                                     float* __restrict__ Y, int n) {
  __shared__ float Ws[512];
  int tid = threadIdx.x;
  Ws[tid] = W[tid];
  Ws[tid + 256] = W[tid + 256];
  __syncthreads();
  int row = blockIdx.x * 256 + tid;
  if (row >= n) return;
  const float4* A4 = (const float4*)(A + (size_t)row * 128);
  float a0 = 0.f, a1 = 0.f, a2 = 0.f, a3 = 0.f;
#pragma unroll
  for (int k4 = 0; k4 < 32; ++k4) {
    float4 a = A4[k4];
    const float* w = &Ws[k4 * 16];
    a0 += a.x * w[0] + a.y * w[4] + a.z * w[8] + a.w * w[12];
    a1 += a.x * w[1] + a.y * w[5] + a.z * w[9] + a.w * w[13];
    a2 += a.x * w[2] + a.y * w[6] + a.z * w[10] + a.w * w[14];
    a3 += a.x * w[3] + a.y * w[7] + a.z * w[11] + a.w * w[15];
  }
  *(float4*)(Y + (size_t)row * 4) = make_float4(a0, a1, a2, a3);
}

// Gather-form propagate, 4 feats: 1 thread per node.
__global__ __launch_bounds__(256) void gather4_k(const int* __restrict__ col,
                                                 const int* __restrict__ rowptr,
                                                 const float* __restrict__ dinv,
                                                 const float* __restrict__ y,
                                                 const float* __restrict__ b2,
                                                 float* __restrict__ out, int n) {
  int node = blockIdx.x * 256 + threadIdx.x;
  if (node >= n) return;
  const int beg = rowptr[node], end = rowptr[node + 1];
  float ax = 0.f, ay = 0.f, az = 0.f, aw = 0.f;
  int p = beg;
  for (; p + 2 <= end; p += 2) {
    int s0 = col[p], s1 = col[p + 1];
    float d0 = dinv[s0], d1 = dinv[s1];
    float4 y0 = *(const float4*)(y + (size_t)s0 * 4);
    float4 y1 = *(const float4*)(y + (size_t)s1 * 4);
    ax += d0 * y0.x + d1 * y1.x;
    ay += d0 * y0.y + d1 * y1.y;
    az += d0 * y0.z + d1 * y1.z;
    aw += d0 * y0.w + d1 * y1.w;
  }
  for (; p < end; ++p) {
    int s = col[p];
    float ds = dinv[s];
    float4 yv = *(const float4*)(y + (size_t)s * 4);
    ax += ds * yv.x;
    ay += ds * yv.y;
    az += ds * yv.z;
    aw += ds * yv.w;
  }
  const float di = dinv[node];
  float4 yd = *(const float4*)(y + (size_t)node * 4);
  float4 o;
  o.x = di * (ax + di * yd.x) + b2[0];
  o.y = di * (ay + di * yd.y) + b2[1];
  o.z = di * (az + di * yd.z) + b2[2];
  o.w = di * (aw + di * yd.w) + b2[3];
  *(float4*)(out + (size_t)node * 4) = o;
}

extern "C" void kernel_launch(void* const* d_in, const int* in_sizes, int n_in,
                              void* d_out, int out_size, void* d_ws, size_t ws_size,
                              hipStream_t stream) {
  const float* clinical = (const float*)d_in[0];
  const float* mel = (const float*)d_in[1];
  const int* ei = (const int*)d_in[2];
  const float* W_mel = (const float*)d_in[3];
  const float* b_mel = (const float*)d_in[4];
  const float* W_cat = (const float*)d_in[5];
  const float* b_cat = (const float*)d_in[6];
  const float* W1 = (const float*)d_in[7];
  const float* b1 = (const float*)d_in[8];
  const float* W2 = (const float*)d_in[9];
  const float* b2 = (const float*)d_in[10];
  float* out = (float*)d_out;

  const int N = in_sizes[0] / 64;   // 100000
  const int E = in_sizes[2] / 2;    // 1600000
  const int B = (N + 255) / 256;    // scan blocks (391)

  // Workspace layout:
  //   bufA [N*128] f | bufB [N*128] f | dinv [N] f | ybuf [N*4] f |
  //   degi [N] i | rowptr [N+1] i | fill [N] i | partial [512] i |
  //   excl [512] i | col [E] i
  float* bufA = (float*)d_ws;
  float* bufB = bufA + (size_t)N * 128;
  float* dinv = bufB + (size_t)N * 128;
  float* ybuf = dinv + N;
  int* degi = (int*)(ybuf + (size_t)N * 4);
  int* rowptr = degi + N;
  int* fill = rowptr + (N + 1);
  int* partial = fill + N;
  int* excl = partial + 512;
  int* col = excl + 512;

  const dim3 blk(256);

  // ---- CSR build + dinv
  zero_int_k<<<(2 * N + 255) / 256, blk, 0, stream>>>(degi, 2 * N);  // degi + rowptr-ish? no: degi,N then fill later
  // (zeroes degi[N] and rowptr[N+1] area partially; fill zeroed separately below)
  count_deg_k<<<(E + 255) / 256, blk, 0, stream>>>(ei, degi, E);
  dinv_k<<<B, blk, 0, stream>>>(degi, dinv, N);
  scan_reduce_k<<<B, blk, 0, stream>>>(degi, partial, N);
  scan_partials_k<<<1, 512, 0, stream>>>(partial, excl, B, rowptr, N, E);
  scan_final_k<<<B, blk, 0, stream>>>(degi, excl, rowptr, N);
  zero_int_k<<<B, blk, 0, stream>>>(fill, N);
  fill_col_k<<<(E + 255) / 256, blk, 0, stream>>>(ei, rowptr, fill, col, E);

  // ---- dense pipeline
  gemm128_k<true, true><<<(N + 63) / 64, blk, 0, stream>>>(mel, 1024, W_mel, b_mel, bufA, N);
  gemm_cat_k<<<(N + 63) / 64, blk, 0, stream>>>(clinical, bufA, W_cat, b_cat, bufB, N);
  gemm128_k<false, false><<<(N + 63) / 64, blk, 0, stream>>>(bufB, 128, W1, nullptr, bufA, N);

  // ---- propagate 1 (fused finish+relu), bufA(h) -> bufB(x3)
  gather128_k<true><<<(N + 1) / 2, blk, 0, stream>>>(col, rowptr, dinv, bufA, b1, bufB, N);

  // ---- y = x3 @ W2 -> ybuf
  gemm_small4_k<<<(N + 255) / 256, blk, 0, stream>>>(bufB, W2, ybuf, N);

  // ---- propagate 2 (fused finish), ybuf -> out
  gather4_k<<<(N + 255) / 256, blk, 0, stream>>>(col, rowptr, dinv, ybuf, b2, out, N);
}

// Round 3
// 1173.952 us; speedup vs baseline: 1.6065x; 1.1170x over previous
//
#include <hip/hip_runtime.h>
#include <cstdint>

// ---------------------------------------------------------------------------
// MultiModalClinicalGCN — round 3: mel GEMM (K=1024) -> bf16 MFMA
//   m  = relu(mel @ W_mel + b_mel)   [N,128]   <-- MFMA 16x16x32 bf16
//   x2 = relu([clinical|m] @ W_cat)  [N,128]   fp32 tiled
//   h  = x2 @ W1                     [N,128]   fp32 tiled
//   x3 = relu(gather(h))                       CSR gather
//   y  = x3 @ W2                     [N,4]
//   out= gather(y) + b2              [N,4]
// ---------------------------------------------------------------------------

typedef short short4_t __attribute__((ext_vector_type(4)));
typedef short short8_t __attribute__((ext_vector_type(8)));
typedef float floatx4 __attribute__((ext_vector_type(4)));

__device__ __forceinline__ short f2bf(float f) {
  union { float f; unsigned u; } v;
  v.f = f;
  unsigned r = v.u + 0x7fffu + ((v.u >> 16) & 1u);  // RNE
  return (short)(r >> 16);
}

// ---------------- edge utils / CSR build (unchanged from round 2) ----------
__device__ __forceinline__ bool detect_i64(const int* __restrict__ ei) {
  int nz = 0;
#pragma unroll
  for (int i = 1; i < 64; i += 2) nz |= ei[i];
  return nz == 0;
}
__device__ __forceinline__ int load_src(const int* __restrict__ ei, int e, bool is64) {
  return is64 ? ei[2 * e] : ei[e];
}
__device__ __forceinline__ int load_dst(const int* __restrict__ ei, int e, int E, bool is64) {
  return is64 ? ei[2 * (E + e)] : ei[E + e];
}

__global__ __launch_bounds__(256) void zero_int_k(int* __restrict__ p, int n) {
  int i = blockIdx.x * 256 + threadIdx.x;
  if (i < n) p[i] = 0;
}

__global__ __launch_bounds__(256) void count_deg_k(const int* __restrict__ ei,
                                                   int* __restrict__ degi, int E) {
  const bool is64 = detect_i64(ei);
  int e = blockIdx.x * 256 + threadIdx.x;
  if (e < E) atomicAdd(&degi[load_dst(ei, e, E, is64)], 1);
}

__global__ __launch_bounds__(256) void dinv_k(const int* __restrict__ degi,
                                              float* __restrict__ dinv, int n) {
  int i = blockIdx.x * 256 + threadIdx.x;
  if (i < n) dinv[i] = rsqrtf((float)degi[i] + 1.0f);  // +1 self-loop
}

__global__ __launch_bounds__(256) void scan_reduce_k(const int* __restrict__ degi,
                                                     int* __restrict__ partial, int n) {
  __shared__ int s[256];
  int t = threadIdx.x;
  int i = blockIdx.x * 256 + t;
  s[t] = (i < n) ? degi[i] : 0;
  __syncthreads();
#pragma unroll
  for (int off = 128; off > 0; off >>= 1) {
    if (t < off) s[t] += s[t + off];
    __syncthreads();
  }
  if (t == 0) partial[blockIdx.x] = s[0];
}

__global__ __launch_bounds__(512) void scan_partials_k(const int* __restrict__ partial,
                                                       int* __restrict__ excl, int B,
                                                       int* __restrict__ rowptr, int n, int E) {
  __shared__ int s[512];
  int t = threadIdx.x;
  int v = (t < B) ? partial[t] : 0;
  s[t] = v;
  __syncthreads();
  for (int off = 1; off < 512; off <<= 1) {
    int x = (t >= off) ? s[t - off] : 0;
    __syncthreads();
    s[t] += x;
    __syncthreads();
  }
  if (t < B) excl[t] = s[t] - v;
  if (t == 0) rowptr[n] = E;
}

__global__ __launch_bounds__(256) void scan_final_k(const int* __restrict__ degi,
                                                    const int* __restrict__ excl,
                                                    int* __restrict__ rowptr, int n) {
  __shared__ int s[256];
  int t = threadIdx.x;
  int i = blockIdx.x * 256 + t;
  int v = (i < n) ? degi[i] : 0;
  s[t] = v;
  __syncthreads();
  for (int off = 1; off < 256; off <<= 1) {
    int x = (t >= off) ? s[t - off] : 0;
    __syncthreads();
    s[t] += x;
    __syncthreads();
  }
  if (i < n) rowptr[i] = excl[blockIdx.x] + s[t] - v;
}

__global__ __launch_bounds__(256) void fill_col_k(const int* __restrict__ ei,
                                                  const int* __restrict__ rowptr,
                                                  int* __restrict__ fill,
                                                  int* __restrict__ col, int E) {
  const bool is64 = detect_i64(ei);
  int e = blockIdx.x * 256 + threadIdx.x;
  if (e < E) {
    int s = load_src(ei, e, is64);
    int d = load_dst(ei, e, E, is64);
    int pos = rowptr[d] + atomicAdd(&fill[d], 1);
    col[pos] = s;
  }
}

// --------------- W_mel [1024,128] fp32 -> Wt [128,1024] bf16 ---------------
__global__ __launch_bounds__(256) void convW_k(const float* __restrict__ W,
                                               short* __restrict__ Wt) {
  int idx = blockIdx.x * 256 + threadIdx.x;  // 131072
  int nn = idx >> 10;                        // 0..127
  int k = idx & 1023;                        // 0..1023
  Wt[idx] = f2bf(W[(size_t)k * 128 + nn]);
}

// ---------------------------------------------------------------------------
// MFMA bf16 GEMM: C[n,128] = relu(A[n,1024] @ W + bias)
// Block = 256 thr (4 waves), tile 128 rows x 128 cols. BK = 64.
// Wave w: rows w*32..w*32+31 => 2 row-tiles x 8 col-tiles of 16x16x32 MFMA.
// A staged fp32->bf16 into LDS (stride 72: 2-way bank alias = free).
// Wt is pre-transposed bf16 [n][k] so B-frags are 16B-contiguous ds_read_b128.
// ---------------------------------------------------------------------------
__global__ __launch_bounds__(256) void mel_gemm_mfma_k(const float* __restrict__ A,
                                                       const short* __restrict__ Wt,
                                                       const float* __restrict__ bias,
                                                       float* __restrict__ C, int n) {
  __shared__ short Asm[128][72];
  __shared__ short Bsm[128][72];
  const int tid = threadIdx.x;
  const int row0 = blockIdx.x * 128;
  const int lane = tid & 63;
  const int wv = tid >> 6;
  const int quad = lane >> 4;
  const int cbase = lane & 15;

  floatx4 acc[2][8];
#pragma unroll
  for (int tr = 0; tr < 2; ++tr)
#pragma unroll
    for (int tc = 0; tc < 8; ++tc) acc[tr][tc] = (floatx4){0.f, 0.f, 0.f, 0.f};

  for (int kc = 0; kc < 16; ++kc) {  // K = 1024, BK = 64
    __syncthreads();
    // stage A: 128 rows x 64 cols fp32 -> bf16
#pragma unroll
    for (int j = 0; j < 8; ++j) {
      int idx = j * 256 + tid;       // 0..2047 float4 chunks
      int row = idx >> 4, c4 = idx & 15;
      int grow = row0 + row;
      floatx4 v = (floatx4){0.f, 0.f, 0.f, 0.f};
      if (grow < n) v = *(const floatx4*)(A + (size_t)grow * 1024 + kc * 64 + c4 * 4);
      short4_t s4;
      s4[0] = f2bf(v[0]); s4[1] = f2bf(v[1]); s4[2] = f2bf(v[2]); s4[3] = f2bf(v[3]);
      *(short4_t*)&Asm[row][c4 * 4] = s4;
    }
    // stage B: 128 n-rows x 64 k-cols bf16 (already transposed in Wt)
#pragma unroll
    for (int j = 0; j < 8; ++j) {
      int idx = j * 256 + tid;
      int nr = idx >> 4, c4 = idx & 15;
      *(short4_t*)&Bsm[nr][c4 * 4] =
          *(const short4_t*)(Wt + (size_t)nr * 1024 + kc * 64 + c4 * 4);
    }
    __syncthreads();
#pragma unroll
    for (int kk = 0; kk < 2; ++kk) {  // two 32-k MFMA steps
      short8_t af[2], bf[8];
#pragma unroll
      for (int tr = 0; tr < 2; ++tr)
        af[tr] = *(const short8_t*)&Asm[wv * 32 + tr * 16 + cbase][kk * 32 + quad * 8];
#pragma unroll
      for (int tc = 0; tc < 8; ++tc)
        bf[tc] = *(const short8_t*)&Bsm[tc * 16 + cbase][kk * 32 + quad * 8];
#pragma unroll
      for (int tr = 0; tr < 2; ++tr)
#pragma unroll
        for (int tc = 0; tc < 8; ++tc)
          acc[tr][tc] = __builtin_amdgcn_mfma_f32_16x16x32_bf16(af[tr], bf[tc],
                                                                acc[tr][tc], 0, 0, 0);
    }
  }
  // epilogue: C[row][col], col = tc*16+cbase, row = row0+wv*32+tr*16+quad*4+r
  float bb[8];
#pragma unroll
  for (int tc = 0; tc < 8; ++tc) bb[tc] = bias[tc * 16 + cbase];
#pragma unroll
  for (int tr = 0; tr < 2; ++tr) {
#pragma unroll
    for (int r = 0; r < 4; ++r) {
      int grow = row0 + wv * 32 + tr * 16 + quad * 4 + r;
      if (grow < n) {
#pragma unroll
        for (int tc = 0; tc < 8; ++tc) {
          float v = acc[tr][tc][r] + bb[tc];
          C[(size_t)grow * 128 + tc * 16 + cbase] = fmaxf(v, 0.f);
        }
      }
    }
  }
}

// ---------------------------------------------------------------------------
// fp32 tiled GEMM (used for K=128 h = x2@W1)
// ---------------------------------------------------------------------------
template <bool RELU, bool HASBIAS>
__global__ __launch_bounds__(256) void gemm128_k(const float* __restrict__ A, int K,
                                                 const float* __restrict__ B,
                                                 const float* __restrict__ bias,
                                                 float* __restrict__ C, int n) {
  __shared__ float As[64][33];
  __shared__ float4 Bs[32][32];
  const int tid = threadIdx.x;
  const int tx = tid & 31, ty = tid >> 5;
  const int row0 = blockIdx.x * 64;
  float acc[8][4];
#pragma unroll
  for (int i = 0; i < 8; ++i)
#pragma unroll
    for (int j = 0; j < 4; ++j) acc[i][j] = 0.f;

  const int nChunks = K >> 5;
  for (int kc = 0; kc < nChunks; ++kc) {
    __syncthreads();
#pragma unroll
    for (int j = 0; j < 2; ++j) {
      int idx = tid + j * 256;
      int ar = idx >> 3, ac4 = idx & 7;
      int grow = row0 + ar;
      float4 v = make_float4(0.f, 0.f, 0.f, 0.f);
      if (grow < n) v = *(const float4*)(A + (size_t)grow * K + kc * 32 + ac4 * 4);
      As[ar][ac4 * 4 + 0] = v.x;
      As[ar][ac4 * 4 + 1] = v.y;
      As[ar][ac4 * 4 + 2] = v.z;
      As[ar][ac4 * 4 + 3] = v.w;
    }
#pragma unroll
    for (int j = 0; j < 4; ++j) {
      int idx = tid + j * 256;
      int br = idx >> 5, bc4 = idx & 31;
      Bs[br][bc4] = *(const float4*)(B + (size_t)(kc * 32 + br) * 128 + bc4 * 4);
    }
    __syncthreads();
#pragma unroll
    for (int kk = 0; kk < 32; ++kk) {
      float4 b = Bs[kk][tx];
#pragma unroll
      for (int i = 0; i < 8; ++i) {
        float a = As[ty * 8 + i][kk];
        acc[i][0] += a * b.x;
        acc[i][1] += a * b.y;
        acc[i][2] += a * b.z;
        acc[i][3] += a * b.w;
      }
    }
  }
  float4 bb = make_float4(0.f, 0.f, 0.f, 0.f);
  if (HASBIAS) bb = *(const float4*)(bias + tx * 4);
#pragma unroll
  for (int i = 0; i < 8; ++i) {
    int grow = row0 + ty * 8 + i;
    if (grow < n) {
      float4 o;
      o.x = acc[i][0] + bb.x;
      o.y = acc[i][1] + bb.y;
      o.z = acc[i][2] + bb.z;
      o.w = acc[i][3] + bb.w;
      if (RELU) {
        o.x = fmaxf(o.x, 0.f);
        o.y = fmaxf(o.y, 0.f);
        o.z = fmaxf(o.z, 0.f);
        o.w = fmaxf(o.w, 0.f);
      }
      *(float4*)(C + (size_t)grow * 128 + tx * 4) = o;
    }
  }
}

// A = [clinical(64) | m(128)] fused (K = 192), relu + bias.
__global__ __launch_bounds__(256) void gemm_cat_k(const float* __restrict__ A1,
                                                  const float* __restrict__ A2,
                                                  const float* __restrict__ B,
                                                  const float* __restrict__ bias,
                                                  float* __restrict__ C, int n) {
  __shared__ float As[64][33];
  __shared__ float4 Bs[32][32];
  const int tid = threadIdx.x;
  const int tx = tid & 31, ty = tid >> 5;
  const int row0 = blockIdx.x * 64;
  float acc[8][4];
#pragma unroll
  for (int i = 0; i < 8; ++i)
#pragma unroll
    for (int j = 0; j < 4; ++j) acc[i][j] = 0.f;

  for (int kc = 0; kc < 6; ++kc) {
    __syncthreads();
#pragma unroll
    for (int j = 0; j < 2; ++j) {
      int idx = tid + j * 256;
      int ar = idx >> 3, ac4 = idx & 7;
      int grow = row0 + ar;
      int kcol = kc * 32 + ac4 * 4;
      float4 v = make_float4(0.f, 0.f, 0.f, 0.f);
      if (grow < n) {
        v = (kcol < 64) ? *(const float4*)(A1 + (size_t)grow * 64 + kcol)
                        : *(const float4*)(A2 + (size_t)grow * 128 + (kcol - 64));
      }
      As[ar][ac4 * 4 + 0] = v.x;
      As[ar][ac4 * 4 + 1] = v.y;
      As[ar][ac4 * 4 + 2] = v.z;
      As[ar][ac4 * 4 + 3] = v.w;
    }
#pragma unroll
    for (int j = 0; j < 4; ++j) {
      int idx = tid + j * 256;
      int br = idx >> 5, bc4 = idx & 31;
      Bs[br][bc4] = *(const float4*)(B + (size_t)(kc * 32 + br) * 128 + bc4 * 4);
    }
    __syncthreads();
#pragma unroll
    for (int kk = 0; kk < 32; ++kk) {
      float4 b = Bs[kk][tx];
#pragma unroll
      for (int i = 0; i < 8; ++i) {
        float a = As[ty * 8 + i][kk];
        acc[i][0] += a * b.x;
        acc[i][1] += a * b.y;
        acc[i][2] += a * b.z;
        acc[i][3] += a * b.w;
      }
    }
  }
  float4 bb = *(const float4*)(bias + tx * 4);
#pragma unroll
  for (int i = 0; i < 8; ++i) {
    int grow = row0 + ty * 8 + i;
    if (grow < n) {
      float4 o;
      o.x = fmaxf(acc[i][0] + bb.x, 0.f);
      o.y = fmaxf(acc[i][1] + bb.y, 0.f);
      o.z = fmaxf(acc[i][2] + bb.z, 0.f);
      o.w = fmaxf(acc[i][3] + bb.w, 0.f);
      *(float4*)(C + (size_t)grow * 128 + tx * 4) = o;
    }
  }
}

// ---------------------------------------------------------------------------
// Gather-form propagate, 128 feats: 128 threads per node (block = 2 nodes).
// ---------------------------------------------------------------------------
template <bool RELU>
__global__ __launch_bounds__(256) void gather128_k(const int* __restrict__ col,
                                                   const int* __restrict__ rowptr,
                                                   const float* __restrict__ dinv,
                                                   const float* __restrict__ h,
                                                   const float* __restrict__ bias,
                                                   float* __restrict__ out, int n) {
  const int node = blockIdx.x * 2 + (threadIdx.x >> 7);
  const int f = threadIdx.x & 127;
  if (node >= n) return;
  const int beg = rowptr[node], end = rowptr[node + 1];
  float acc = 0.f;
  int p = beg;
  for (; p + 4 <= end; p += 4) {
    int s0 = col[p], s1 = col[p + 1], s2 = col[p + 2], s3 = col[p + 3];
    float d0 = dinv[s0], d1 = dinv[s1], d2 = dinv[s2], d3 = dinv[s3];
    float h0 = h[(size_t)s0 * 128 + f];
    float h1 = h[(size_t)s1 * 128 + f];
    float h2 = h[(size_t)s2 * 128 + f];
    float h3 = h[(size_t)s3 * 128 + f];
    acc += d0 * h0 + d1 * h1 + d2 * h2 + d3 * h3;
  }
  for (; p < end; ++p) {
    int s = col[p];
    acc += dinv[s] * h[(size_t)s * 128 + f];
  }
  const float di = dinv[node];
  float v = di * (acc + di * h[(size_t)node * 128 + f]) + bias[f];
  if (RELU) v = fmaxf(v, 0.f);
  out[(size_t)node * 128 + f] = v;
}

// y[n,4] = A[n,128] @ W[128,4]
__global__ __launch_bounds__(256) void gemm_small4_k(const float* __restrict__ A,
                                                     const float* __restrict__ W,
                                                     float* __restrict__ Y, int n) {
  __shared__ float Ws[512];
  int tid = threadIdx.x;
  Ws[tid] = W[tid];
  Ws[tid + 256] = W[tid + 256];
  __syncthreads();
  int row = blockIdx.x * 256 + tid;
  if (row >= n) return;
  const float4* A4 = (const float4*)(A + (size_t)row * 128);
  float a0 = 0.f, a1 = 0.f, a2 = 0.f, a3 = 0.f;
#pragma unroll
  for (int k4 = 0; k4 < 32; ++k4) {
    float4 a = A4[k4];
    const float* w = &Ws[k4 * 16];
    a0 += a.x * w[0] + a.y * w[4] + a.z * w[8] + a.w * w[12];
    a1 += a.x * w[1] + a.y * w[5] + a.z * w[9] + a.w * w[13];
    a2 += a.x * w[2] + a.y * w[6] + a.z * w[10] + a.w * w[14];
    a3 += a.x * w[3] + a.y * w[7] + a.z * w[11] + a.w * w[15];
  }
  *(float4*)(Y + (size_t)row * 4) = make_float4(a0, a1, a2, a3);
}

// Gather-form propagate, 4 feats: 1 thread per node.
__global__ __launch_bounds__(256) void gather4_k(const int* __restrict__ col,
                                                 const int* __restrict__ rowptr,
                                                 const float* __restrict__ dinv,
                                                 const float* __restrict__ y,
                                                 const float* __restrict__ b2,
                                                 float* __restrict__ out, int n) {
  int node = blockIdx.x * 256 + threadIdx.x;
  if (node >= n) return;
  const int beg = rowptr[node], end = rowptr[node + 1];
  float ax = 0.f, ay = 0.f, az = 0.f, aw = 0.f;
  int p = beg;
  for (; p + 2 <= end; p += 2) {
    int s0 = col[p], s1 = col[p + 1];
    float d0 = dinv[s0], d1 = dinv[s1];
    float4 y0 = *(const float4*)(y + (size_t)s0 * 4);
    float4 y1 = *(const float4*)(y + (size_t)s1 * 4);
    ax += d0 * y0.x + d1 * y1.x;
    ay += d0 * y0.y + d1 * y1.y;
    az += d0 * y0.z + d1 * y1.z;
    aw += d0 * y0.w + d1 * y1.w;
  }
  for (; p < end; ++p) {
    int s = col[p];
    float ds = dinv[s];
    float4 yv = *(const float4*)(y + (size_t)s * 4);
    ax += ds * yv.x;
    ay += ds * yv.y;
    az += ds * yv.z;
    aw += ds * yv.w;
  }
  const float di = dinv[node];
  float4 yd = *(const float4*)(y + (size_t)node * 4);
  float4 o;
  o.x = di * (ax + di * yd.x) + b2[0];
  o.y = di * (ay + di * yd.y) + b2[1];
  o.z = di * (az + di * yd.z) + b2[2];
  o.w = di * (aw + di * yd.w) + b2[3];
  *(float4*)(out + (size_t)node * 4) = o;
}

extern "C" void kernel_launch(void* const* d_in, const int* in_sizes, int n_in,
                              void* d_out, int out_size, void* d_ws, size_t ws_size,
                              hipStream_t stream) {
  const float* clinical = (const float*)d_in[0];
  const float* mel = (const float*)d_in[1];
  const int* ei = (const int*)d_in[2];
  const float* W_mel = (const float*)d_in[3];
  const float* b_mel = (const float*)d_in[4];
  const float* W_cat = (const float*)d_in[5];
  const float* b_cat = (const float*)d_in[6];
  const float* W1 = (const float*)d_in[7];
  const float* b1 = (const float*)d_in[8];
  const float* W2 = (const float*)d_in[9];
  const float* b2 = (const float*)d_in[10];
  float* out = (float*)d_out;

  const int N = in_sizes[0] / 64;   // 100000
  const int E = in_sizes[2] / 2;    // 1600000
  const int B = (N + 255) / 256;    // scan blocks (391)

  // Workspace layout:
  //   bufA [N*128] f | bufB [N*128] f | dinv [N] f | ybuf [N*4] f |
  //   degi [N] i | rowptr [N+1] i | fill [N] i | partial [512] i |
  //   excl [512] i | col [E] i | Wt [1024*128] short
  float* bufA = (float*)d_ws;
  float* bufB = bufA + (size_t)N * 128;
  float* dinv = bufB + (size_t)N * 128;
  float* ybuf = dinv + N;
  int* degi = (int*)(ybuf + (size_t)N * 4);
  int* rowptr = degi + N;
  int* fill = rowptr + (N + 1);
  int* partial = fill + N;
  int* excl = partial + 512;
  int* col = excl + 512;
  short* Wt = (short*)(col + E);

  const dim3 blk(256);

  // ---- CSR build + dinv + weight conversion
  zero_int_k<<<(N + 255) / 256, blk, 0, stream>>>(degi, N);
  count_deg_k<<<(E + 255) / 256, blk, 0, stream>>>(ei, degi, E);
  dinv_k<<<B, blk, 0, stream>>>(degi, dinv, N);
  scan_reduce_k<<<B, blk, 0, stream>>>(degi, partial, N);
  scan_partials_k<<<1, 512, 0, stream>>>(partial, excl, B, rowptr, N, E);
  scan_final_k<<<B, blk, 0, stream>>>(degi, excl, rowptr, N);
  zero_int_k<<<B, blk, 0, stream>>>(fill, N);
  fill_col_k<<<(E + 255) / 256, blk, 0, stream>>>(ei, rowptr, fill, col, E);
  convW_k<<<512, blk, 0, stream>>>(W_mel, Wt);

  // ---- dense pipeline
  mel_gemm_mfma_k<<<(N + 127) / 128, blk, 0, stream>>>(mel, Wt, b_mel, bufA, N);
  gemm_cat_k<<<(N + 63) / 64, blk, 0, stream>>>(clinical, bufA, W_cat, b_cat, bufB, N);
  gemm128_k<false, false><<<(N + 63) / 64, blk, 0, stream>>>(bufB, 128, W1, nullptr, bufA, N);

  // ---- propagate 1 (fused finish+relu), bufA(h) -> bufB(x3)
  gather128_k<true><<<(N + 1) / 2, blk, 0, stream>>>(col, rowptr, dinv, bufA, b1, bufB, N);

  // ---- y = x3 @ W2 -> ybuf
  gemm_small4_k<<<(N + 255) / 256, blk, 0, stream>>>(bufB, W2, ybuf, N);

  // ---- propagate 2 (fused finish), ybuf -> out
  gather4_k<<<(N + 255) / 256, blk, 0, stream>>>(col, rowptr, dinv, ybuf, b2, out, N);
}